// Round 1
// baseline (462.653 us; speedup 1.0000x reference)
//
#include <hip/hip_runtime.h>
#include <math.h>

// Problem constants (from reference setup_inputs)
#define BB 32
#define AA 3
#define HH 64
#define WW 64
#define CC 80
#define NN 2048
#define CH (5 + CC)                 // 85 channels per cell
#define NCELL (BB * AA * HH * WW)   // 393216 cells

// bce_logits(x, t) = max(x,0) - x*t + log1p(exp(-|x|))
__device__ __forceinline__ float bce_pos(float x) {  // t = 1
    return fmaxf(x, 0.f) - x + log1pf(expf(-fabsf(x)));
}
__device__ __forceinline__ float bce_neg(float x) {  // t = 0
    return fmaxf(x, 0.f) + log1pf(expf(-fabsf(x)));
}

// Kernel 1: per-target work. N=2048 threads.
// mask bits: bit0 = obj set at this cell; bit1 = noobj suppressed (some anchor IoU > 0.5)
// acc[0] += sum of squared bbox error; acc[1] += sum of class BCE
__global__ void yolo_per_target(const float* __restrict__ pred,
                                const float* __restrict__ target,
                                const float* __restrict__ anchors,
                                unsigned int* __restrict__ mask,
                                float* __restrict__ acc) {
    int n = blockIdx.x * blockDim.x + threadIdx.x;
    float lx = 0.f, lc = 0.f;
    if (n < NN) {
        float tb = target[n * 6 + 0];
        float tl = target[n * 6 + 1];
        float tx = target[n * 6 + 2] * (float)HH;
        float ty = target[n * 6 + 3] * (float)HH;
        float tw = target[n * 6 + 4] * (float)HH;
        float th = target[n * 6 + 5] * (float)HH;
        int b = (int)tb;
        int label = (int)tl;
        int wi = (int)tw;
        int hi = (int)th;

        // IoU vs 3 anchors, argmax (strict > => first occurrence, matches jnp.argmax)
        float area_t = tw * th;
        float ious[AA];
        float best = -1.f;
        int bi = 0;
        #pragma unroll
        for (int a = 0; a < AA; a++) {
            float aw = anchors[a * 2 + 0];
            float ah = anchors[a * 2 + 1];
            float inter = fminf(aw, tw) * fminf(ah, th);
            float iou = inter / (aw * ah + area_t - inter);
            ious[a] = iou;
            if (iou > best) { best = iou; bi = a; }
        }

        // Scatters: obj bit at argmax anchor cell, suppress bit where IoU > 0.5
        #pragma unroll
        for (int a = 0; a < AA; a++) {
            int cell = ((b * AA + a) * HH + hi) * WW + wi;
            unsigned int bits = 0u;
            if (a == bi) bits |= 1u;
            if (ious[a] > 0.5f) bits |= 2u;   // keep = (iou <= 0.5); suppress if keep==0
            if (bits) atomicOr(&mask[cell], bits);
        }

        // bbox target: [frac(txy), log(twh / anchor[bi])]
        float t0 = tx - floorf(tx);
        float t1 = ty - floorf(ty);
        float t2 = logf(tw / anchors[bi * 2 + 0]);
        float t3 = logf(th / anchors[bi * 2 + 1]);

        long pbase = (long)(((b * AA + bi) * HH + hi) * WW + wi) * CH;
        float d0 = pred[pbase + 0] - t0;
        float d1 = pred[pbase + 1] - t1;
        float d2 = pred[pbase + 2] - t2;
        float d3 = pred[pbase + 3] - t3;
        lx = d0 * d0 + d1 * d1 + d2 * d2 + d3 * d3;

        // class BCE vs one-hot(label)
        for (int c = 0; c < CC; c++) {
            float x = pred[pbase + 5 + c];
            lc += (c == label) ? bce_pos(x) : bce_neg(x);
        }
    }
    // wave-64 reduce, one atomic per wave
    #pragma unroll
    for (int off = 32; off > 0; off >>= 1) {
        lx += __shfl_down(lx, off, 64);
        lc += __shfl_down(lc, off, 64);
    }
    if ((threadIdx.x & 63) == 0) {
        atomicAdd(&acc[0], lx);
        atomicAdd(&acc[1], lc);
    }
}

// Kernel 2: confidence pass over all cells.
// acc[2] += conf_sum; acc[3] += n_obj; acc[4] += n_noobj
__global__ void yolo_conf(const float* __restrict__ pred,
                          const unsigned int* __restrict__ mask,
                          float* __restrict__ acc) {
    int i = blockIdx.x * blockDim.x + threadIdx.x;
    float cs = 0.f, nob = 0.f, nno = 0.f;
    if (i < NCELL) {
        unsigned int m = mask[i];
        float x = pred[(long)i * CH + 4];
        if (m & 1u) {                 // obj cell
            cs = bce_pos(x);
            nob = 1.f;
        } else if (!(m & 2u)) {       // plain noobj cell (not suppressed)
            cs = bce_neg(x);
            nno = 1.f;
        }                             // suppressed: contributes nothing
    }
    #pragma unroll
    for (int off = 32; off > 0; off >>= 1) {
        cs  += __shfl_down(cs,  off, 64);
        nob += __shfl_down(nob, off, 64);
        nno += __shfl_down(nno, off, 64);
    }
    if ((threadIdx.x & 63) == 0) {
        atomicAdd(&acc[2], cs);
        atomicAdd(&acc[3], nob);
        atomicAdd(&acc[4], nno);
    }
}

// Kernel 3: combine
__global__ void yolo_finalize(const float* __restrict__ acc, float* __restrict__ out) {
    float loss_xywh = acc[0] / ((float)NN * 4.f);
    float loss_cls  = acc[1] / ((float)NN * (float)CC);
    float loss_conf = acc[2] / (acc[3] + acc[4]);
    out[0] = loss_xywh + loss_conf + loss_cls;
}

extern "C" void kernel_launch(void* const* d_in, const int* in_sizes, int n_in,
                              void* d_out, int out_size, void* d_ws, size_t ws_size,
                              hipStream_t stream) {
    const float* pred    = (const float*)d_in[0];
    const float* target  = (const float*)d_in[1];
    const float* anchors = (const float*)d_in[2];
    (void)in_sizes; (void)n_in; (void)out_size; (void)ws_size;

    unsigned int* mask = (unsigned int*)d_ws;
    float* acc = (float*)((char*)d_ws + (size_t)NCELL * sizeof(unsigned int));

    // zero mask + 8 accumulator floats (ws is re-poisoned to 0xAA before every call)
    hipMemsetAsync(d_ws, 0, (size_t)NCELL * sizeof(unsigned int) + 8 * sizeof(float), stream);

    yolo_per_target<<<(NN + 255) / 256, 256, 0, stream>>>(pred, target, anchors, mask, acc);
    yolo_conf<<<(NCELL + 255) / 256, 256, 0, stream>>>(pred, mask, acc);
    yolo_finalize<<<1, 1, 0, stream>>>(acc, (float*)d_out);
}

// Round 2
// 192.589 us; speedup vs baseline: 2.4023x; 2.4023x over previous
//
#include <hip/hip_runtime.h>
#include <math.h>

// Problem constants (from reference setup_inputs)
#define BB 32
#define AA 3
#define HH 64
#define WW 64
#define CC 80
#define NN 2048
#define CH (5 + CC)                 // 85 channels per cell
#define NCELL (BB * AA * HH * WW)   // 393216 cells

// conf kernel geometry: 384 blocks x 256 threads x 4 cells/thread = 393216
#define CONF_BLOCKS 384
#define CONF_CPT 4
#define CONF_STRIDE (CONF_BLOCKS * 256)   // 98304

// per-target kernel: one wave per target, 4 waves/block -> 512 blocks
#define TGT_BLOCKS (NN / 4)

// bce_logits(x, t) = max(x,0) - x*t + log1p(exp(-|x|))
__device__ __forceinline__ float bce_pos(float x) {  // t = 1
    return fmaxf(x, 0.f) - x + log1pf(expf(-fabsf(x)));
}
__device__ __forceinline__ float bce_neg(float x) {  // t = 0
    return fmaxf(x, 0.f) + log1pf(expf(-fabsf(x)));
}

__device__ __forceinline__ float wave_reduce(float v) {
    #pragma unroll
    for (int off = 32; off > 0; off >>= 1) v += __shfl_down(v, off, 64);
    return v;
}

// Kernel 1: per-target work, ONE WAVE PER TARGET.
// mask bits: bit0 = obj set at this cell; bit1 = noobj suppressed (some anchor IoU > 0.5)
// tgt_partial[block] = {sum sq bbox err, sum class BCE} (block-reduced, no global atomics)
__global__ void yolo_per_target(const float* __restrict__ pred,
                                const float* __restrict__ target,
                                const float* __restrict__ anchors,
                                unsigned int* __restrict__ mask,
                                float* __restrict__ tgt_partial) {
    __shared__ float s_lx[4], s_lc[4];
    int wave = threadIdx.x >> 6;          // 0..3
    int lane = threadIdx.x & 63;
    int n = blockIdx.x * 4 + wave;        // target index, exact (NN = 4*TGT_BLOCKS)

    // all lanes read the 6-float target row (broadcast via cache)
    float tx = target[n * 6 + 2] * (float)HH;
    float ty = target[n * 6 + 3] * (float)HH;
    float tw = target[n * 6 + 4] * (float)HH;
    float th = target[n * 6 + 5] * (float)HH;
    int b     = (int)target[n * 6 + 0];
    int label = (int)target[n * 6 + 1];
    int wi = (int)tw;
    int hi = (int)th;

    // IoU vs 3 anchors, strict-> first-occurrence argmax (matches jnp.argmax)
    float area_t = tw * th;
    float ious[AA];
    float best = -1.f;
    int bi = 0;
    #pragma unroll
    for (int a = 0; a < AA; a++) {
        float aw = anchors[a * 2 + 0];
        float ah = anchors[a * 2 + 1];
        float inter = fminf(aw, tw) * fminf(ah, th);
        float iou = inter / (aw * ah + area_t - inter);
        ious[a] = iou;
        if (iou > best) { best = iou; bi = a; }
    }

    // lanes 0..2 scatter mask bits for anchor a=lane (sparse addresses, no contention)
    if (lane < AA) {
        int a = lane;
        int cell = ((b * AA + a) * HH + hi) * WW + wi;
        unsigned int bits = 0u;
        if (a == bi) bits |= 1u;
        if (ious[a] > 0.5f) bits |= 2u;
        if (bits) atomicOr(&mask[cell], bits);
    }

    long pbase = (long)(((b * AA + bi) * HH + hi) * WW + wi) * CH;

    float lx = 0.f, lc = 0.f;
    // bbox: lanes 0..3, one component each (coalesced 4-float read)
    if (lane < 4) {
        float t0 = tx - floorf(tx);
        float t1 = ty - floorf(ty);
        float t2 = logf(tw / anchors[bi * 2 + 0]);
        float t3 = logf(th / anchors[bi * 2 + 1]);
        float tt = (lane == 0) ? t0 : (lane == 1) ? t1 : (lane == 2) ? t2 : t3;
        float d = pred[pbase + lane] - tt;
        lx = d * d;
    }
    // class BCE: lane handles class=lane and class=lane+64 (coalesced 80-float read)
    {
        float x = pred[pbase + 5 + lane];           // classes 0..63
        lc = (lane == label) ? bce_pos(x) : bce_neg(x);
        if (lane < CC - 64) {
            int c2 = 64 + lane;                     // classes 64..79
            float x2 = pred[pbase + 5 + c2];
            lc += (c2 == label) ? bce_pos(x2) : bce_neg(x2);
        }
    }

    lx = wave_reduce(lx);
    lc = wave_reduce(lc);
    if (lane == 0) { s_lx[wave] = lx; s_lc[wave] = lc; }
    __syncthreads();
    if (threadIdx.x == 0) {
        tgt_partial[blockIdx.x * 2 + 0] = s_lx[0] + s_lx[1] + s_lx[2] + s_lx[3];
        tgt_partial[blockIdx.x * 2 + 1] = s_lc[0] + s_lc[1] + s_lc[2] + s_lc[3];
    }
}

// Kernel 2: confidence pass over all cells. 4 independent cells/thread (MLP),
// block-level LDS reduction, per-block partials -> NO global atomics.
__global__ void yolo_conf(const float* __restrict__ pred,
                          const unsigned int* __restrict__ mask,
                          float* __restrict__ conf_partial) {
    __shared__ float s_cs[4], s_ob[4], s_no[4];
    int tid = blockIdx.x * blockDim.x + threadIdx.x;
    float cs = 0.f, nob = 0.f, nno = 0.f;

    // issue all 4 mask loads + 4 pred loads independently for MLP
    unsigned int m[CONF_CPT];
    float x[CONF_CPT];
    #pragma unroll
    for (int k = 0; k < CONF_CPT; k++) {
        int cell = tid + k * CONF_STRIDE;           // exact coverage, no bounds check
        m[k] = mask[cell];
        x[k] = pred[(long)cell * CH + 4];
    }
    #pragma unroll
    for (int k = 0; k < CONF_CPT; k++) {
        if (m[k] & 1u) {                // obj cell
            cs += bce_pos(x[k]);
            nob += 1.f;
        } else if (!(m[k] & 2u)) {      // plain noobj cell
            cs += bce_neg(x[k]);
            nno += 1.f;
        }
    }

    cs = wave_reduce(cs);
    nob = wave_reduce(nob);
    nno = wave_reduce(nno);
    int wave = threadIdx.x >> 6, lane = threadIdx.x & 63;
    if (lane == 0) { s_cs[wave] = cs; s_ob[wave] = nob; s_no[wave] = nno; }
    __syncthreads();
    if (threadIdx.x == 0) {
        conf_partial[blockIdx.x * 3 + 0] = s_cs[0] + s_cs[1] + s_cs[2] + s_cs[3];
        conf_partial[blockIdx.x * 3 + 1] = s_ob[0] + s_ob[1] + s_ob[2] + s_ob[3];
        conf_partial[blockIdx.x * 3 + 2] = s_no[0] + s_no[1] + s_no[2] + s_no[3];
    }
}

// Kernel 3: one wave sums all partials and combines.
__global__ void yolo_finalize(const float* __restrict__ conf_partial,
                              const float* __restrict__ tgt_partial,
                              float* __restrict__ out) {
    int lane = threadIdx.x;               // 64 threads
    float cs = 0.f, nob = 0.f, nno = 0.f, lx = 0.f, lc = 0.f;
    for (int i = lane; i < CONF_BLOCKS; i += 64) {
        cs  += conf_partial[i * 3 + 0];
        nob += conf_partial[i * 3 + 1];
        nno += conf_partial[i * 3 + 2];
    }
    for (int i = lane; i < TGT_BLOCKS; i += 64) {
        lx += tgt_partial[i * 2 + 0];
        lc += tgt_partial[i * 2 + 1];
    }
    cs = wave_reduce(cs);
    nob = wave_reduce(nob);
    nno = wave_reduce(nno);
    lx = wave_reduce(lx);
    lc = wave_reduce(lc);
    if (lane == 0) {
        float loss_xywh = lx / ((float)NN * 4.f);
        float loss_cls  = lc / ((float)NN * (float)CC);
        float loss_conf = cs / (nob + nno);
        out[0] = loss_xywh + loss_conf + loss_cls;
    }
}

extern "C" void kernel_launch(void* const* d_in, const int* in_sizes, int n_in,
                              void* d_out, int out_size, void* d_ws, size_t ws_size,
                              hipStream_t stream) {
    const float* pred    = (const float*)d_in[0];
    const float* target  = (const float*)d_in[1];
    const float* anchors = (const float*)d_in[2];
    (void)in_sizes; (void)n_in; (void)out_size; (void)ws_size;

    unsigned int* mask = (unsigned int*)d_ws;                      // NCELL u32
    float* conf_partial = (float*)((char*)d_ws + (size_t)NCELL * 4);          // 384*3
    float* tgt_partial  = conf_partial + CONF_BLOCKS * 3;                     // 512*2

    // zero only the mask (partials are fully overwritten each call)
    hipMemsetAsync(mask, 0, (size_t)NCELL * sizeof(unsigned int), stream);

    yolo_per_target<<<TGT_BLOCKS, 256, 0, stream>>>(pred, target, anchors, mask, tgt_partial);
    yolo_conf<<<CONF_BLOCKS, 256, 0, stream>>>(pred, mask, conf_partial);
    yolo_finalize<<<1, 64, 0, stream>>>(conf_partial, tgt_partial, (float*)d_out);
}